// Round 4
// baseline (1977.952 us; speedup 1.0000x reference)
//
#include <hip/hip_runtime.h>
#include <math.h>

typedef __attribute__((ext_vector_type(8))) short short8;
typedef __attribute__((ext_vector_type(4))) float f32x4;

#define EPI_BF16   0
#define EPI_SCORES 1
#define EPI_R      2
#define EPI_Z      3
#define EPI_N      4

__device__ __forceinline__ unsigned short f2bf(float f) {
    unsigned int u = __float_as_uint(f);
    u += 0x7fffu + ((u >> 16) & 1u);
    return (unsigned short)(u >> 16);
}
__device__ __forceinline__ float bf2f(unsigned short s) {
    return __uint_as_float(((unsigned int)s) << 16);
}

struct alignas(8) us4 { unsigned short a, b, c, d; };

#define GLD_LDS16(gp, lp) \
    __builtin_amdgcn_global_load_lds((const __attribute__((address_space(1))) unsigned int*)(gp), \
                                     (__attribute__((address_space(3))) unsigned int*)(lp), 16, 0, 0)

#define BAR    __builtin_amdgcn_s_barrier()
#define LGKM0  do { asm volatile("s_waitcnt lgkmcnt(0)" ::: "memory"); \
                    __builtin_amdgcn_sched_barrier(0); } while (0)
#define VMC4   asm volatile("s_waitcnt vmcnt(4)" ::: "memory")
#define VMC0   asm volatile("s_waitcnt vmcnt(0)" ::: "memory")

// ============================================================================
// 256x256 tile, BK=64, 512 threads (8 waves: 2M x 4N), m201-style 8-phase
// pipeline (8 phases per 2 K-tiles), ONE barrier per phase.
// LDS 128 KiB: buf{0,1} x { A-half0, A-half1, B-half0, B-half1 } x 16 KiB.
// Per 2 K-tiles (T0->buf0 phases a-d, T1->buf1 phases a'-d'):
//   ph  slot: stage half-tile (2 gload_lds)   reads          MFMA
//   a   T1.B0 -> buf1                          A0+B0 of buf0  q(0,0)
//   b   T1.B1 -> buf1                          A1+B1 of buf0  q(0,1)
//   c   T2a.A0 -> buf0 (buf0 free after b)     -              q(1,1)
//   d   T2a.A1 -> buf0                         -              q(1,0)
//   a'  T2a.B0 -> buf0                         A0+B0 of buf1  q(0,0)
//   b'  T2a.B1 -> buf0                         A1+B1 of buf1  q(0,1)
//   c'  T2b.A0 -> buf1                         -              q(1,1)
//   d'  T2b.A1 -> buf1                         -              q(1,0)
// vmcnt(4) before ph a / a' barriers (newest 2 half-tiles may stay in flight).
// Hazards: H1 (global->LDS RAW): per-wave vmcnt + barrier precede reads.
// H2 (LDS WAR): every staged region's readers lgkm0'd >=1 barrier earlier.
// ============================================================================
template<int EPI, int SWZ>
__global__ void __launch_bounds__(512, 2)
gemm256(const unsigned short* __restrict__ A, long long sAb, int lda,
        const unsigned short* __restrict__ Bt, long long sBb, int ldb,
        const float* __restrict__ bias,
        void* __restrict__ C, long long sCb, int ldc,
        int K, float scale,
        const float* __restrict__ hptr,
        const unsigned short* __restrict__ updptr)
{
    extern __shared__ char smem[];   // 131072 B

    const int z = blockIdx.z;
    A  += (size_t)z * (size_t)sAb;
    Bt += (size_t)z * (size_t)sBb;

    int bx, by;
    if (SWZ) {
        const int bid = blockIdx.y * 8 + blockIdx.x;   // grid (8,128)
        const int xcd = bid & 7, i = bid >> 3;
        bx = i & 7;
        by = (xcd << 4) | (i >> 3);
    } else {
        bx = blockIdx.x; by = blockIdx.y;
    }
    const int m0 = by * 256;
    const int n0 = bx * 256;

    const int tid = threadIdx.x;
    const int w  = tid >> 6;      // wave 0..7
    const int l  = tid & 63;
    const int wr = w >> 2;        // 0..1 (M half: 128 rows)
    const int wc = w & 3;         // 0..3 (N quarter: 64 cols)
    const int lr = l & 15;
    const int lg = l >> 4;
    const int rs = (lr & 7) << 4; // read-side XOR swizzle

    const int srw = l >> 3;                        // staging row-within-8
    const int scb = ((l & 7) << 4) ^ (srw << 4);   // inverse-swizzled src col byte

    const long long ldab = (long long)lda * 2;
    const long long ldbb = (long long)ldb * 2;

    f32x4 acc[2][4][4] = {};
    short8 a[8][2], b[4][2];

// LDS regions (16 KiB each)
#define AR(buf, half) (smem + (buf)*65536 + (half)*16384)
#define BR(buf, half) (smem + (buf)*65536 + 32768 + (half)*16384)

// stage one 128x64 half-tile (2 x global_load_lds per thread)
#define STAGE_H(gbase, ldbytes, r0abs, kt, region) { \
    _Pragma("unroll") \
    for (int j = 0; j < 2; ++j) { \
        const char* g_ = (const char*)(gbase) + \
            (size_t)((r0abs) + j*64 + w*8 + srw) * (ldbytes) + (size_t)(kt)*2 + scb; \
        GLD_LDS16(g_, (region) + j*8192 + (w<<10)); } }

#define LDA8(MH, buf) { \
    const char* Ab_ = AR(buf, wr); \
    _Pragma("unroll") \
    for (int mf = 0; mf < 4; ++mf) { \
        const int row_ = (MH)*64 + mf*16 + lr; \
        _Pragma("unroll") \
        for (int kk = 0; kk < 2; ++kk) \
            a[(MH)*4+mf][kk] = *(const short8*)(Ab_ + row_*128 + ((kk*64 + lg*16) ^ rs)); } }

#define LDB4(BH, buf) { \
    const char* Bb_ = BR(buf, wc >> 1); \
    _Pragma("unroll") \
    for (int nf = 0; nf < 2; ++nf) { \
        const int row_ = (wc&1)*64 + (BH)*32 + nf*16 + lr; \
        _Pragma("unroll") \
        for (int kk = 0; kk < 2; ++kk) \
            b[(BH)*2+nf][kk] = *(const short8*)(Bb_ + row_*128 + ((kk*64 + lg*16) ^ rs)); } }

// kk outer: dependent MFMAs on same acc are 8 apart
#define MMA16(MH, BH) { \
    __builtin_amdgcn_s_setprio(1); \
    _Pragma("unroll") \
    for (int kk = 0; kk < 2; ++kk) \
    _Pragma("unroll") \
    for (int mf = 0; mf < 4; ++mf) \
    _Pragma("unroll") \
    for (int nf = 0; nf < 2; ++nf) \
        acc[MH][mf][(BH)*2+nf] = __builtin_amdgcn_mfma_f32_16x16x32_bf16( \
            a[(MH)*4+mf][kk], b[(BH)*2+nf][kk], acc[MH][mf][(BH)*2+nf], 0, 0, 0); \
    __builtin_amdgcn_s_setprio(0); }

    // prologue: T0 all 4 halves, then T1.A0, T1.A1  (12 gload_lds)
    STAGE_H(A,  ldab, m0 + 0,   0,  AR(0,0));
    STAGE_H(A,  ldab, m0 + 128, 0,  AR(0,1));
    STAGE_H(Bt, ldbb, n0 + 0,   0,  BR(0,0));
    STAGE_H(Bt, ldbb, n0 + 128, 0,  BR(0,1));
    STAGE_H(A,  ldab, m0 + 0,   64, AR(1,0));
    STAGE_H(A,  ldab, m0 + 128, 64, AR(1,1));

    const int NIT = K >> 7;                    // 2 K-tiles per iteration (K % 128 == 0, NIT >= 2)
    for (int it = 0; it < NIT - 1; ++it) {
        const int kt0 = it << 7;
        // ---- s=0: compute buf0 (tile 2it) ----
        VMC4; BAR;                                            // T0 landed
        STAGE_H(Bt, ldbb, n0 + 0,   kt0 + 64,  BR(1,0));      // T1.B0
        LDA8(0, 0); LDB4(0, 0);
        LGKM0; MMA16(0, 0);
        BAR;
        STAGE_H(Bt, ldbb, n0 + 128, kt0 + 64,  BR(1,1));      // T1.B1
        LDA8(1, 0); LDB4(1, 0);
        LGKM0; MMA16(0, 1);
        BAR;
        STAGE_H(A,  ldab, m0 + 0,   kt0 + 128, AR(0,0));      // T2a.A0
        MMA16(1, 1);
        BAR;
        STAGE_H(A,  ldab, m0 + 128, kt0 + 128, AR(0,1));      // T2a.A1
        MMA16(1, 0);
        // ---- s=1: compute buf1 (tile 2it+1) ----
        VMC4; BAR;                                            // T1 landed
        STAGE_H(Bt, ldbb, n0 + 0,   kt0 + 128, BR(0,0));      // T2a.B0
        LDA8(0, 1); LDB4(0, 1);
        LGKM0; MMA16(0, 0);
        BAR;
        STAGE_H(Bt, ldbb, n0 + 128, kt0 + 128, BR(0,1));      // T2a.B1
        LDA8(1, 1); LDB4(1, 1);
        LGKM0; MMA16(0, 1);
        BAR;
        STAGE_H(A,  ldab, m0 + 0,   kt0 + 192, AR(1,0));      // T2b.A0
        MMA16(1, 1);
        BAR;
        STAGE_H(A,  ldab, m0 + 128, kt0 + 192, AR(1,1));      // T2b.A1
        MMA16(1, 0);
    }
    // ---- peeled last iteration: T0=NT-2 (buf0), T1=NT-1 (buf1) ----
    {
        const int kt0 = (NIT - 1) << 7;
        VMC4; BAR;
        STAGE_H(Bt, ldbb, n0 + 0,   kt0 + 64, BR(1,0));
        LDA8(0, 0); LDB4(0, 0); LGKM0; MMA16(0, 0);
        BAR;
        STAGE_H(Bt, ldbb, n0 + 128, kt0 + 64, BR(1,1));
        LDA8(1, 0); LDB4(1, 0); LGKM0; MMA16(0, 1);
        BAR; MMA16(1, 1);
        BAR; MMA16(1, 0);
        VMC0; BAR;
        LDA8(0, 1); LDB4(0, 1); LGKM0; MMA16(0, 0);
        BAR;
        LDA8(1, 1); LDB4(1, 1); LGKM0; MMA16(0, 1);
        BAR; MMA16(1, 1);
        BAR; MMA16(1, 0);
    }

    // epilogue
    const int Mb = gridDim.y << 8;
    const size_t zc = (size_t)z * (size_t)sCb;
    #pragma unroll
    for (int mh = 0; mh < 2; ++mh) {
        #pragma unroll
        for (int mf = 0; mf < 4; ++mf) {
            #pragma unroll
            for (int nf = 0; nf < 4; ++nf) {
                const int col = n0 + wc * 64 + nf * 16 + lr;
                const float bval = (EPI == EPI_BF16) ? bias[col] : 0.0f;
                #pragma unroll
                for (int r = 0; r < 4; ++r) {
                    const int row = m0 + wr * 128 + mh * 64 + mf * 16 + lg * 4 + r;
                    float v = acc[mh][mf][nf][r] + bval;
                    if (EPI == EPI_BF16) {
                        ((unsigned short*)C)[zc + (size_t)row * ldc + col] = f2bf(v);
                    } else if (EPI == EPI_SCORES) {
                        ((float*)C)[zc + (size_t)row * ldc + col] = v * scale;
                    } else if (EPI == EPI_R) {
                        const size_t flat = (size_t)z * Mb + row;
                        const float hh = hptr[flat * 1024 + col];
                        const float sg = 1.0f / (1.0f + __expf(-v));
                        ((unsigned short*)C)[flat * 2048 + 1024 + col] = f2bf(hh * sg);
                    } else if (EPI == EPI_Z) {
                        const size_t flat = (size_t)z * Mb + row;
                        const float sg = 1.0f / (1.0f + __expf(-v));
                        ((unsigned short*)C)[flat * 1024 + col] = f2bf(sg);
                    } else { // EPI_N
                        const size_t flat = (size_t)z * Mb + row;
                        const float u  = bf2f(updptr[flat * 1024 + col]);
                        const float hh = hptr[flat * 1024 + col];
                        ((float*)C)[flat * 1024 + col] = (1.0f - u) * hh + u * tanhf(v);
                    }
                }
            }
        }
    }
#undef AR
#undef BR
#undef STAGE_H
#undef LDA8
#undef LDB4
#undef MMA16
}

// ============================================================================
// memory-bound helper kernels
// ============================================================================

__global__ void __launch_bounds__(256)
prep_xh(const float* __restrict__ x, const float* __restrict__ h, unsigned short* __restrict__ xh)
{
    const size_t t = (size_t)blockIdx.x * 256 + threadIdx.x;
    const size_t f = t * 4;
    const size_t row = f >> 10, col = f & 1023;
    const float4 vx = *(const float4*)(x + f);
    const float4 vh = *(const float4*)(h + f);
    us4 ox = { f2bf(vx.x), f2bf(vx.y), f2bf(vx.z), f2bf(vx.w) };
    us4 oh = { f2bf(vh.x), f2bf(vh.y), f2bf(vh.z), f2bf(vh.w) };
    *(us4*)(xh + row * 2048 + col)        = ox;
    *(us4*)(xh + row * 2048 + 1024 + col) = oh;
}

__global__ void __launch_bounds__(256)
transpose_w(const float* __restrict__ W, unsigned short* __restrict__ WT, int N)
{
    __shared__ float t[32][33];
    const int k0 = blockIdx.y * 32, n0 = blockIdx.x * 32;
    const int tx = threadIdx.x & 31, ty = threadIdx.x >> 5;
    #pragma unroll
    for (int i = 0; i < 4; ++i)
        t[ty + i * 8][tx] = W[(size_t)(k0 + ty + i * 8) * N + n0 + tx];
    __syncthreads();
    #pragma unroll
    for (int i = 0; i < 4; ++i)
        WT[(size_t)(n0 + ty + i * 8) * 2048 + k0 + tx] = f2bf(t[tx][ty + i * 8]);
}

__global__ void __launch_bounds__(256)
transpose_v(const unsigned short* __restrict__ V, unsigned short* __restrict__ Vt)
{
    __shared__ unsigned short t[32][34];
    const int z = blockIdx.z;
    const unsigned short* in = V + (size_t)z * 512 * 2048;
    unsigned short* outp = Vt + (size_t)z * 1024 * 512;
    const int c0 = blockIdx.x * 32, r0 = blockIdx.y * 32;
    const int tx = threadIdx.x & 31, ty = threadIdx.x >> 5;
    #pragma unroll
    for (int i = 0; i < 4; ++i)
        t[ty + i * 8][tx] = in[(size_t)(r0 + ty + i * 8) * 2048 + c0 + tx];
    __syncthreads();
    #pragma unroll
    for (int i = 0; i < 4; ++i)
        outp[(size_t)(c0 + ty + i * 8) * 512 + r0 + tx] = t[tx][ty + i * 8];
}

__global__ void __launch_bounds__(256)
softmax512(const float* __restrict__ S, unsigned short* __restrict__ P)
{
    const int row = blockIdx.x * 4 + (threadIdx.x >> 6);
    const int l = threadIdx.x & 63;
    const float* s = S + (size_t)row * 512;
    const float4 v0 = ((const float4*)s)[l];
    const float4 v1 = ((const float4*)s)[64 + l];
    float m = fmaxf(fmaxf(fmaxf(v0.x, v0.y), fmaxf(v0.z, v0.w)),
                    fmaxf(fmaxf(v1.x, v1.y), fmaxf(v1.z, v1.w)));
    #pragma unroll
    for (int d = 32; d; d >>= 1) m = fmaxf(m, __shfl_xor(m, d));
    float e0 = __expf(v0.x - m), e1 = __expf(v0.y - m), e2 = __expf(v0.z - m), e3 = __expf(v0.w - m);
    float e4 = __expf(v1.x - m), e5 = __expf(v1.y - m), e6 = __expf(v1.z - m), e7 = __expf(v1.w - m);
    float sum = e0 + e1 + e2 + e3 + e4 + e5 + e6 + e7;
    #pragma unroll
    for (int d = 32; d; d >>= 1) sum += __shfl_xor(sum, d);
    const float inv = 1.0f / sum;
    unsigned short* p = P + (size_t)row * 512;
    us4 aa = { f2bf(e0 * inv), f2bf(e1 * inv), f2bf(e2 * inv), f2bf(e3 * inv) };
    us4 bb = { f2bf(e4 * inv), f2bf(e5 * inv), f2bf(e6 * inv), f2bf(e7 * inv) };
    ((us4*)p)[l] = aa;
    ((us4*)p)[64 + l] = bb;
}

__global__ void __launch_bounds__(256)
layernorm1024(float* __restrict__ Y, const float* __restrict__ gamma, const float* __restrict__ beta)
{
    const int row = blockIdx.x * 4 + (threadIdx.x >> 6);
    const int l = threadIdx.x & 63;
    float* p = Y + (size_t)row * 1024;
    float4 v[4];
    float s = 0.0f, s2 = 0.0f;
    #pragma unroll
    for (int i = 0; i < 4; ++i) {
        v[i] = ((const float4*)p)[i * 64 + l];
        s  += v[i].x + v[i].y + v[i].z + v[i].w;
        s2 += v[i].x * v[i].x + v[i].y * v[i].y + v[i].z * v[i].z + v[i].w * v[i].w;
    }
    #pragma unroll
    for (int d = 32; d; d >>= 1) { s += __shfl_xor(s, d); s2 += __shfl_xor(s2, d); }
    const float mu = s * (1.0f / 1024.0f);
    const float var = s2 * (1.0f / 1024.0f) - mu * mu;
    const float inv = rsqrtf(var + 1e-5f);
    #pragma unroll
    for (int i = 0; i < 4; ++i) {
        const float4 gv = ((const float4*)gamma)[i * 64 + l];
        const float4 bv = ((const float4*)beta)[i * 64 + l];
        float4 o;
        o.x = (v[i].x - mu) * inv * gv.x + bv.x;
        o.y = (v[i].y - mu) * inv * gv.y + bv.y;
        o.z = (v[i].z - mu) * inv * gv.z + bv.z;
        o.w = (v[i].w - mu) * inv * gv.w + bv.w;
        ((float4*)p)[i * 64 + l] = o;
    }
}

__global__ void __launch_bounds__(256)
concat_bias(const float* __restrict__ a, const float* __restrict__ b,
            const float* __restrict__ c, float* __restrict__ o)
{
    const int i = blockIdx.x * 256 + threadIdx.x;
    o[i] = (i < 512) ? a[i] : (i < 1024) ? b[i - 512] : c[i - 1024];
}

extern "C" void kernel_launch(void* const* d_in, const int* in_sizes, int n_in,
                              void* d_out, int out_size, void* d_ws, size_t ws_size,
                              hipStream_t stream)
{
    (void)in_sizes; (void)n_in; (void)out_size; (void)ws_size;

    const float* x = (const float*)d_in[0];
    const float* h = (const float*)d_in[1];
    const float* Wf[9]; const float* bia[9];
    for (int g = 0; g < 3; ++g)
        for (int j = 0; j < 3; ++j) {
            Wf[g * 3 + j]  = (const float*)d_in[2 + g * 6 + j * 2];
            bia[g * 3 + j] = (const float*)d_in[2 + g * 6 + j * 2 + 1];
        }
    const float* gamma = (const float*)d_in[20];
    const float* beta  = (const float*)d_in[21];
    float* out = (float*)d_out;

    const int LDS_BYTES = 131072;
    hipFuncSetAttribute((const void*)gemm256<EPI_BF16, 1>,   hipFuncAttributeMaxDynamicSharedMemorySize, LDS_BYTES);
    hipFuncSetAttribute((const void*)gemm256<EPI_SCORES, 0>, hipFuncAttributeMaxDynamicSharedMemorySize, LDS_BYTES);
    hipFuncSetAttribute((const void*)gemm256<EPI_R, 0>,      hipFuncAttributeMaxDynamicSharedMemorySize, LDS_BYTES);
    hipFuncSetAttribute((const void*)gemm256<EPI_Z, 0>,      hipFuncAttributeMaxDynamicSharedMemorySize, LDS_BYTES);
    hipFuncSetAttribute((const void*)gemm256<EPI_N, 0>,      hipFuncAttributeMaxDynamicSharedMemorySize, LDS_BYTES);

    char* ws = (char*)d_ws;
    size_t off = 0;
    auto alloc = [&](size_t bytes) -> void* {
        void* p = ws + off; off += (bytes + 255) & ~(size_t)255; return p;
    };
    unsigned short* xh  = (unsigned short*)alloc((size_t)32768 * 2048 * 2);
    unsigned short* WT  = (unsigned short*)alloc((size_t)12582912 * 2);
    unsigned short* QKV = (unsigned short*)alloc((size_t)32768 * 2048 * 2);
    unsigned short* Vt  = (unsigned short*)alloc((size_t)32768 * 1024 * 2);
    float*          Sc  = (float*)alloc((size_t)64 * 512 * 512 * 4);
    unsigned short* Pb  = (unsigned short*)alloc((size_t)64 * 512 * 512 * 2);
    unsigned short* upd = (unsigned short*)alloc((size_t)32768 * 1024 * 2);
    float*          bct = (float*)alloc((size_t)3 * 2048 * 4);

    size_t wtoff[9];
    {
        size_t o = 0;
        for (int g = 0; g < 3; ++g) {
            wtoff[g * 3 + 0] = o; o += (size_t)512 * 2048;
            wtoff[g * 3 + 1] = o; o += (size_t)512 * 2048;
            wtoff[g * 3 + 2] = o; o += (size_t)1024 * 2048;
        }
    }

    prep_xh<<<32768, 256, 0, stream>>>(x, h, xh);
    for (int i = 0; i < 9; ++i) {
        const int N = (i % 3 == 2) ? 1024 : 512;
        transpose_w<<<dim3(N / 32, 64, 1), 256, 0, stream>>>(Wf[i], WT + wtoff[i], N);
    }
    for (int g = 0; g < 3; ++g)
        concat_bias<<<8, 256, 0, stream>>>(bia[g * 3 + 0], bia[g * 3 + 1], bia[g * 3 + 2], bct + g * 2048);

    const float scscale = 0.044194173824159216f; // 1/sqrt(512)

    auto gate = [&](int g, int epi) {
        const unsigned short* wT = WT + wtoff[g * 3 + 0];
        // fused QKV projection: (32768 x 2048) @ (2048 x 2048)^T, XCD-swizzled
        gemm256<EPI_BF16, 1><<<dim3(8, 128, 1), 512, LDS_BYTES, stream>>>(
            xh, 0, 2048, wT, 0, 2048, bct + g * 2048, QKV, 0, 2048, 2048, 0.0f, nullptr, nullptr);
        transpose_v<<<dim3(32, 16, 64), 256, 0, stream>>>(QKV + 1024, Vt);
        // scores = Q @ K^T * scale (batched over 64)
        gemm256<EPI_SCORES, 0><<<dim3(2, 2, 64), 512, LDS_BYTES, stream>>>(
            QKV, 1048576, 2048, QKV + 512, 1048576, 2048, nullptr,
            Sc, 262144, 512, 512, scscale, nullptr, nullptr);
        softmax512<<<8192, 256, 0, stream>>>(Sc, Pb);
        // PV (batched), fused gate epilogue
        if (epi == EPI_Z)
            gemm256<EPI_Z, 0><<<dim3(4, 2, 64), 512, LDS_BYTES, stream>>>(
                Pb, 262144, 512, Vt, 524288, 512, nullptr, upd, 0, 1024, 512, 0.0f, nullptr, nullptr);
        else if (epi == EPI_R)
            gemm256<EPI_R, 0><<<dim3(4, 2, 64), 512, LDS_BYTES, stream>>>(
                Pb, 262144, 512, Vt, 524288, 512, nullptr, xh, 0, 2048, 512, 0.0f, h, nullptr);
        else
            gemm256<EPI_N, 0><<<dim3(4, 2, 64), 512, LDS_BYTES, stream>>>(
                Pb, 262144, 512, Vt, 524288, 512, nullptr, out, 0, 1024, 512, 0.0f, h, upd);
    };

    gate(1, EPI_Z);  // update = sigmoid(z-attn)            (reads original xh)
    gate(0, EPI_R);  // xh[:,1024:] = bf16(h * sigmoid(r))  (in-place -> xhr)
    gate(2, EPI_N);  // out = (1-u)*h + u*tanh(n-attn)
    layernorm1024<<<8192, 256, 0, stream>>>(out, gamma, beta);
}

// Round 5
// 1407.032 us; speedup vs baseline: 1.4058x; 1.4058x over previous
//
#include <hip/hip_runtime.h>
#include <math.h>

typedef __attribute__((ext_vector_type(8))) short short8;
typedef __attribute__((ext_vector_type(4))) float f32x4;

#define EPI_BF16   0
#define EPI_SCORES 1
#define EPI_R      2
#define EPI_Z      3
#define EPI_N      4

__device__ __forceinline__ unsigned short f2bf(float f) {
    unsigned int u = __float_as_uint(f);
    u += 0x7fffu + ((u >> 16) & 1u);
    return (unsigned short)(u >> 16);
}
__device__ __forceinline__ float bf2f(unsigned short s) {
    return __uint_as_float(((unsigned int)s) << 16);
}

struct alignas(8) us4 { unsigned short a, b, c, d; };

#define GLD_LDS16(gp, lp) \
    __builtin_amdgcn_global_load_lds((const __attribute__((address_space(1))) unsigned int*)(gp), \
                                     (__attribute__((address_space(3))) unsigned int*)(lp), 16, 0, 0)

#define BAR   do { asm volatile("" ::: "memory"); __builtin_amdgcn_s_barrier(); \
                   asm volatile("" ::: "memory"); } while (0)
#define VMC4  asm volatile("s_waitcnt vmcnt(4)" ::: "memory")
#define VMC0  asm volatile("s_waitcnt vmcnt(0)" ::: "memory")

// ============================================================================
// 256x256 tile, BK=64, 512 threads (8 waves: 2M x 4N).
// Schedule per K-tile (phases; ONE barrier each except ph2 which needs a
// trailing barrier for the ph2-read/ph3-stage WAR on the same LDS rows):
//   ph0: issue LDA(mh0)+LDB(bh0) [12 ds_read]; stage B0(t+1)->buf q; BAR; MMA q00
//   ph1: issue LDB(bh1) [4];                  stage B1(t+1)->buf q; BAR; MMA q01
//   ph2: issue LDA(mh1) [8];                  stage A0(t+2)->buf p; BAR; MMA q11; BAR
//   ph3:                                       stage A1(t+2)->buf p; vmcnt(4); BAR; MMA q10
// ds_reads issue BEFORE the barrier (latency hides in barrier wait); compiler
// inserts fine-grained lgkmcnt before MFMA uses (no explicit full drain).
// A-stage slots match read phases: A0 = rows {0-63,128-191} (read by ph0),
// A1 = rows {64-127,192-255} (read by ph2). B rotates cross-buffer (any split).
// WAR safety: stage(region) is always >= 2 barriers after that region's
// readers' consuming MFMAs, except ph3-stage vs ph2-reads -> extra ph2 BAR.
// vmcnt(4) at ph3 retires through B1(t+1) (queue: A(t+1)x4? already retired,
// B(t+1)x4, A(t+2)x4 in flight) -> tile t+1 fully landed before next ph0.
// LDS 128 KiB: 2 bufs x (A 32KB + B 32KB), XOR-swizzle byte^=(row&7)<<4 via
// inverse-swizzled global source (gload_lds writes linearly).
// ============================================================================
template<int EPI, int SWZ>
__global__ void __launch_bounds__(512, 2)
gemm256(const unsigned short* __restrict__ A, long long sAb, int lda,
        const unsigned short* __restrict__ Bt, long long sBb, int ldb,
        const float* __restrict__ bias,
        void* __restrict__ C, long long sCb, int ldc,
        int K, float scale,
        const float* __restrict__ hptr,
        const unsigned short* __restrict__ updptr)
{
    extern __shared__ char smem[];   // 131072 B

    const int z = blockIdx.z;
    A  += (size_t)z * (size_t)sAb;
    Bt += (size_t)z * (size_t)sBb;

    int bx, by;
    if (SWZ) {
        const int bid = blockIdx.y * 8 + blockIdx.x;   // grid (8,128)
        const int xcd = bid & 7, i = bid >> 3;
        bx = i & 7;
        by = (xcd << 4) | (i >> 3);
    } else {
        bx = blockIdx.x; by = blockIdx.y;
    }
    const int m0 = by * 256;
    const int n0 = bx * 256;

    const int tid = threadIdx.x;
    const int w  = tid >> 6;      // wave 0..7
    const int l  = tid & 63;
    const int wr = w >> 2;        // 0..1 (M half: 128 rows)
    const int wc = w & 3;         // 0..3 (N quarter: 64 cols)
    const int lr = l & 15;
    const int lg = l >> 4;
    const int rs = (lr & 7) << 4; // read-side XOR swizzle

    const int srw = l >> 3;                        // staging row-within-8
    const int scb = ((l & 7) << 4) ^ (srw << 4);   // inverse-swizzled src col byte

    const long long ldab = (long long)lda * 2;
    const long long ldbb = (long long)ldb * 2;

    f32x4 acc[2][4][4] = {};
    short8 a[4][2], b[4][2];

// one gload_lds per thread: stages 64 rows (grow0..+63) x 64k into LDS at ldsoff
#define STAGE1(gbase, ldbytes, grow0, ldsoff) { \
    const char* g_ = (const char*)(gbase) + \
        (size_t)((grow0) + w*8 + srw) * (ldbytes) + scb; \
    GLD_LDS16(g_, smem + (ldsoff) + (w << 10)); }

#define AOFF(buf) ((buf)*65536)
#define BOFF(buf) ((buf)*65536 + 32768)

// slot staging: A0 covers rows {0-63,128-191}, A1 {64-127,192-255} (2 calls each)
#define STAGE_A0(kt, buf) { STAGE1(A, ldab, m0 + 0   + 0*0, AOFF(buf) + 0);      \
                            STAGE1(A + (size_t)(kt)*0, ldab, m0 + 128, AOFF(buf) + 16384); } (void)0
#define STAGE_B0(kt, buf) { STAGE1(Bt, ldbb, n0 + 0,   BOFF(buf) + 0);      \
                            STAGE1(Bt, ldbb, n0 + 128, BOFF(buf) + 16384); } (void)0
#define STAGE_A1(kt, buf) { STAGE1(A, ldab, m0 + 64,  AOFF(buf) + 8192);  \
                            STAGE1(A, ldab, m0 + 192, AOFF(buf) + 24576); } (void)0
#define STAGE_B1(kt, buf) { STAGE1(Bt, ldbb, n0 + 64,  BOFF(buf) + 8192);  \
                            STAGE1(Bt, ldbb, n0 + 192, BOFF(buf) + 24576); } (void)0

#define LDA8(MH, buf) { \
    const char* Ab_ = smem + AOFF(buf); \
    _Pragma("unroll") \
    for (int mf = 0; mf < 4; ++mf) { \
        const int row_ = wr*128 + (MH)*64 + mf*16 + lr; \
        _Pragma("unroll") \
        for (int kk = 0; kk < 2; ++kk) \
            a[mf][kk] = *(const short8*)(Ab_ + row_*128 + ((kk*64 + lg*16) ^ rs)); } }

#define LDB4(BH, buf) { \
    const char* Bb_ = smem + BOFF(buf); \
    _Pragma("unroll") \
    for (int nf = 0; nf < 2; ++nf) { \
        const int row_ = wc*64 + (BH)*32 + nf*16 + lr; \
        _Pragma("unroll") \
        for (int kk = 0; kk < 2; ++kk) \
            b[(BH)*2+nf][kk] = *(const short8*)(Bb_ + row_*128 + ((kk*64 + lg*16) ^ rs)); } }

#define MMA16(MH, BH) { \
    __builtin_amdgcn_s_setprio(1); \
    _Pragma("unroll") \
    for (int kk = 0; kk < 2; ++kk) \
    _Pragma("unroll") \
    for (int mf = 0; mf < 4; ++mf) \
    _Pragma("unroll") \
    for (int nf = 0; nf < 2; ++nf) \
        acc[MH][mf][(BH)*2+nf] = __builtin_amdgcn_mfma_f32_16x16x32_bf16( \
            a[mf][kk], b[(BH)*2+nf][kk], acc[MH][mf][(BH)*2+nf], 0, 0, 0); \
    __builtin_amdgcn_s_setprio(0); }

    // prologue: tile0 (all 4 slots) -> buf0; tile1 A-slots -> buf1. 12 gload/thread.
    {
        const unsigned short* A0p = A;           const unsigned short* B0p = Bt;
        (void)A0p; (void)B0p;
        // tile 0, k-offset 0
        { const long long kb = 0;
          STAGE1(A  + (kb>>1), ldab, m0 + 0,   AOFF(0) + 0);
          STAGE1(A  + (kb>>1), ldab, m0 + 128, AOFF(0) + 16384);
          STAGE1(A  + (kb>>1), ldab, m0 + 64,  AOFF(0) + 8192);
          STAGE1(A  + (kb>>1), ldab, m0 + 192, AOFF(0) + 24576);
          STAGE1(Bt + (kb>>1), ldbb, n0 + 0,   BOFF(0) + 0);
          STAGE1(Bt + (kb>>1), ldbb, n0 + 128, BOFF(0) + 16384);
          STAGE1(Bt + (kb>>1), ldbb, n0 + 64,  BOFF(0) + 8192);
          STAGE1(Bt + (kb>>1), ldbb, n0 + 192, BOFF(0) + 24576); }
        // tile 1, A only
        { const long long kb = 128;              // 64 elems * 2B
          STAGE1(A  + (kb>>1), ldab, m0 + 0,   AOFF(1) + 0);
          STAGE1(A  + (kb>>1), ldab, m0 + 128, AOFF(1) + 16384);
          STAGE1(A  + (kb>>1), ldab, m0 + 64,  AOFF(1) + 8192);
          STAGE1(A  + (kb>>1), ldab, m0 + 192, AOFF(1) + 24576); }
        VMC4;   // 12 outstanding -> wait till tile0's 8 retired
        BAR;
    }

    const int NT = K >> 6;
    for (int t = 0; t < NT; ++t) {
        const int p = t & 1, q = p ^ 1;
        const unsigned short* An = A  + (size_t)(t + 2) * 64;   // tile t+2 A base
        const unsigned short* Bn = Bt + (size_t)(t + 1) * 64;   // tile t+1 B base
        const bool sB = (t + 1 < NT), sA = (t + 2 < NT);

        // ph0
        LDA8(0, p); LDB4(0, p);
        if (sB) { STAGE1(Bn, ldbb, n0 + 0,   BOFF(q) + 0);
                  STAGE1(Bn, ldbb, n0 + 128, BOFF(q) + 16384); }
        BAR;
        MMA16(0, 0);
        // ph1
        LDB4(1, p);
        if (sB) { STAGE1(Bn, ldbb, n0 + 64,  BOFF(q) + 8192);
                  STAGE1(Bn, ldbb, n0 + 192, BOFF(q) + 24576); }
        BAR;
        MMA16(0, 1);
        // ph2
        LDA8(1, p);
        if (sA) { STAGE1(An, ldab, m0 + 0,   AOFF(p) + 0);
                  STAGE1(An, ldab, m0 + 128, AOFF(p) + 16384); }
        BAR;
        MMA16(1, 1);
        BAR;                       // guards ph3-stage vs ph2-reads (same rows)
        // ph3
        if (sA) { STAGE1(An, ldab, m0 + 64,  AOFF(p) + 8192);
                  STAGE1(An, ldab, m0 + 192, AOFF(p) + 24576);
                  VMC4; }
        else if (sB) { VMC0; }
        BAR;
        MMA16(1, 0);
    }

    // epilogue
    const int Mb = gridDim.y << 8;
    const size_t zc = (size_t)z * (size_t)sCb;
    #pragma unroll
    for (int mh = 0; mh < 2; ++mh) {
        #pragma unroll
        for (int mf = 0; mf < 4; ++mf) {
            #pragma unroll
            for (int nf = 0; nf < 4; ++nf) {
                const int col = n0 + wc * 64 + nf * 16 + lr;
                const float bval = (EPI == EPI_BF16) ? bias[col] : 0.0f;
                #pragma unroll
                for (int r = 0; r < 4; ++r) {
                    const int row = m0 + wr * 128 + mh * 64 + mf * 16 + lg * 4 + r;
                    float v = acc[mh][mf][nf][r] + bval;
                    if (EPI == EPI_BF16) {
                        ((unsigned short*)C)[zc + (size_t)row * ldc + col] = f2bf(v);
                    } else if (EPI == EPI_SCORES) {
                        ((float*)C)[zc + (size_t)row * ldc + col] = v * scale;
                    } else if (EPI == EPI_R) {
                        const size_t flat = (size_t)z * Mb + row;
                        const float hh = hptr[flat * 1024 + col];
                        const float sg = 1.0f / (1.0f + __expf(-v));
                        ((unsigned short*)C)[flat * 2048 + 1024 + col] = f2bf(hh * sg);
                    } else if (EPI == EPI_Z) {
                        const size_t flat = (size_t)z * Mb + row;
                        const float sg = 1.0f / (1.0f + __expf(-v));
                        ((unsigned short*)C)[flat * 1024 + col] = f2bf(sg);
                    } else { // EPI_N
                        const size_t flat = (size_t)z * Mb + row;
                        const float u  = bf2f(updptr[flat * 1024 + col]);
                        const float hh = hptr[flat * 1024 + col];
                        ((float*)C)[flat * 1024 + col] = (1.0f - u) * hh + u * tanhf(v);
                    }
                }
            }
        }
    }
#undef STAGE1
#undef AOFF
#undef BOFF
#undef STAGE_A0
#undef STAGE_A1
#undef STAGE_B0
#undef STAGE_B1
#undef LDA8
#undef LDB4
#undef MMA16
}

// ============================================================================
// memory-bound helper kernels
// ============================================================================

__global__ void __launch_bounds__(256)
prep_xh(const float* __restrict__ x, const float* __restrict__ h, unsigned short* __restrict__ xh)
{
    const size_t t = (size_t)blockIdx.x * 256 + threadIdx.x;
    const size_t f = t * 4;
    const size_t row = f >> 10, col = f & 1023;
    const float4 vx = *(const float4*)(x + f);
    const float4 vh = *(const float4*)(h + f);
    us4 ox = { f2bf(vx.x), f2bf(vx.y), f2bf(vx.z), f2bf(vx.w) };
    us4 oh = { f2bf(vh.x), f2bf(vh.y), f2bf(vh.z), f2bf(vh.w) };
    *(us4*)(xh + row * 2048 + col)        = ox;
    *(us4*)(xh + row * 2048 + 1024 + col) = oh;
}

__global__ void __launch_bounds__(256)
transpose_w(const float* __restrict__ W, unsigned short* __restrict__ WT, int N)
{
    __shared__ float t[32][33];
    const int k0 = blockIdx.y * 32, n0 = blockIdx.x * 32;
    const int tx = threadIdx.x & 31, ty = threadIdx.x >> 5;
    #pragma unroll
    for (int i = 0; i < 4; ++i)
        t[ty + i * 8][tx] = W[(size_t)(k0 + ty + i * 8) * N + n0 + tx];
    __syncthreads();
    #pragma unroll
    for (int i = 0; i < 4; ++i)
        WT[(size_t)(n0 + ty + i * 8) * 2048 + k0 + tx] = f2bf(t[tx][ty + i * 8]);
}

__global__ void __launch_bounds__(256)
transpose_v(const unsigned short* __restrict__ V, unsigned short* __restrict__ Vt)
{
    __shared__ unsigned short t[32][34];
    const int z = blockIdx.z;
    const unsigned short* in = V + (size_t)z * 512 * 2048;
    unsigned short* outp = Vt + (size_t)z * 1024 * 512;
    const int c0 = blockIdx.x * 32, r0 = blockIdx.y * 32;
    const int tx = threadIdx.x & 31, ty = threadIdx.x >> 5;
    #pragma unroll
    for (int i = 0; i < 4; ++i)
        t[ty + i * 8][tx] = in[(size_t)(r0 + ty + i * 8) * 2048 + c0 + tx];
    __syncthreads();
    #pragma unroll
    for (int i = 0; i < 4; ++i)
        outp[(size_t)(c0 + ty + i * 8) * 512 + r0 + tx] = t[tx][ty + i * 8];
}

__global__ void __launch_bounds__(256)
softmax512(const float* __restrict__ S, unsigned short* __restrict__ P)
{
    const int row = blockIdx.x * 4 + (threadIdx.x >> 6);
    const int l = threadIdx.x & 63;
    const float* s = S + (size_t)row * 512;
    const float4 v0 = ((const float4*)s)[l];
    const float4 v1 = ((const float4*)s)[64 + l];
    float m = fmaxf(fmaxf(fmaxf(v0.x, v0.y), fmaxf(v0.z, v0.w)),
                    fmaxf(fmaxf(v1.x, v1.y), fmaxf(v1.z, v1.w)));
    #pragma unroll
    for (int d = 32; d; d >>= 1) m = fmaxf(m, __shfl_xor(m, d));
    float e0 = __expf(v0.x - m), e1 = __expf(v0.y - m), e2 = __expf(v0.z - m), e3 = __expf(v0.w - m);
    float e4 = __expf(v1.x - m), e5 = __expf(v1.y - m), e6 = __expf(v1.z - m), e7 = __expf(v1.w - m);
    float sum = e0 + e1 + e2 + e3 + e4 + e5 + e6 + e7;
    #pragma unroll
    for (int d = 32; d; d >>= 1) sum += __shfl_xor(sum, d);
    const float inv = 1.0f / sum;
    unsigned short* p = P + (size_t)row * 512;
    us4 aa = { f2bf(e0 * inv), f2bf(e1 * inv), f2bf(e2 * inv), f2bf(e3 * inv) };
    us4 bb = { f2bf(e4 * inv), f2bf(e5 * inv), f2bf(e6 * inv), f2bf(e7 * inv) };
    ((us4*)p)[l] = aa;
    ((us4*)p)[64 + l] = bb;
}

__global__ void __launch_bounds__(256)
layernorm1024(float* __restrict__ Y, const float* __restrict__ gamma, const float* __restrict__ beta)
{
    const int row = blockIdx.x * 4 + (threadIdx.x >> 6);
    const int l = threadIdx.x & 63;
    float* p = Y + (size_t)row * 1024;
    float4 v[4];
    float s = 0.0f, s2 = 0.0f;
    #pragma unroll
    for (int i = 0; i < 4; ++i) {
        v[i] = ((const float4*)p)[i * 64 + l];
        s  += v[i].x + v[i].y + v[i].z + v[i].w;
        s2 += v[i].x * v[i].x + v[i].y * v[i].y + v[i].z * v[i].z + v[i].w * v[i].w;
    }
    #pragma unroll
    for (int d = 32; d; d >>= 1) { s += __shfl_xor(s, d); s2 += __shfl_xor(s2, d); }
    const float mu = s * (1.0f / 1024.0f);
    const float var = s2 * (1.0f / 1024.0f) - mu * mu;
    const float inv = rsqrtf(var + 1e-5f);
    #pragma unroll
    for (int i = 0; i < 4; ++i) {
        const float4 gv = ((const float4*)gamma)[i * 64 + l];
        const float4 bv = ((const float4*)beta)[i * 64 + l];
        float4 o;
        o.x = (v[i].x - mu) * inv * gv.x + bv.x;
        o.y = (v[i].y - mu) * inv * gv.y + bv.y;
        o.z = (v[i].z - mu) * inv * gv.z + bv.z;
        o.w = (v[i].w - mu) * inv * gv.w + bv.w;
        ((float4*)p)[i * 64 + l] = o;
    }
}

__global__ void __launch_bounds__(256)
concat_bias(const float* __restrict__ a, const float* __restrict__ b,
            const float* __restrict__ c, float* __restrict__ o)
{
    const int i = blockIdx.x * 256 + threadIdx.x;
    o[i] = (i < 512) ? a[i] : (i < 1024) ? b[i - 512] : c[i - 1024];
}

extern "C" void kernel_launch(void* const* d_in, const int* in_sizes, int n_in,
                              void* d_out, int out_size, void* d_ws, size_t ws_size,
                              hipStream_t stream)
{
    (void)in_sizes; (void)n_in; (void)out_size; (void)ws_size;

    const float* x = (const float*)d_in[0];
    const float* h = (const float*)d_in[1];
    const float* Wf[9]; const float* bia[9];
    for (int g = 0; g < 3; ++g)
        for (int j = 0; j < 3; ++j) {
            Wf[g * 3 + j]  = (const float*)d_in[2 + g * 6 + j * 2];
            bia[g * 3 + j] = (const float*)d_in[2 + g * 6 + j * 2 + 1];
        }
    const float* gamma = (const float*)d_in[20];
    const float* beta  = (const float*)d_in[21];
    float* out = (float*)d_out;

    const int LDS_BYTES = 131072;
    hipFuncSetAttribute((const void*)gemm256<EPI_BF16, 1>,   hipFuncAttributeMaxDynamicSharedMemorySize, LDS_BYTES);
    hipFuncSetAttribute((const void*)gemm256<EPI_SCORES, 0>, hipFuncAttributeMaxDynamicSharedMemorySize, LDS_BYTES);
    hipFuncSetAttribute((const void*)gemm256<EPI_R, 0>,      hipFuncAttributeMaxDynamicSharedMemorySize, LDS_BYTES);
    hipFuncSetAttribute((const void*)gemm256<EPI_Z, 0>,      hipFuncAttributeMaxDynamicSharedMemorySize, LDS_BYTES);
    hipFuncSetAttribute((const void*)gemm256<EPI_N, 0>,      hipFuncAttributeMaxDynamicSharedMemorySize, LDS_BYTES);

    char* ws = (char*)d_ws;
    size_t off = 0;
    auto alloc = [&](size_t bytes) -> void* {
        void* p = ws + off; off += (bytes + 255) & ~(size_t)255; return p;
    };
    unsigned short* xh  = (unsigned short*)alloc((size_t)32768 * 2048 * 2);
    unsigned short* WT  = (unsigned short*)alloc((size_t)12582912 * 2);
    unsigned short* QKV = (unsigned short*)alloc((size_t)32768 * 2048 * 2);
    unsigned short* Vt  = (unsigned short*)alloc((size_t)32768 * 1024 * 2);
    float*          Sc  = (float*)alloc((size_t)64 * 512 * 512 * 4);
    unsigned short* Pb  = (unsigned short*)alloc((size_t)64 * 512 * 512 * 2);
    unsigned short* upd = (unsigned short*)alloc((size_t)32768 * 1024 * 2);
    float*          bct = (float*)alloc((size_t)3 * 2048 * 4);

    size_t wtoff[9];
    {
        size_t o = 0;
        for (int g = 0; g < 3; ++g) {
            wtoff[g * 3 + 0] = o; o += (size_t)512 * 2048;
            wtoff[g * 3 + 1] = o; o += (size_t)512 * 2048;
            wtoff[g * 3 + 2] = o; o += (size_t)1024 * 2048;
        }
    }

    prep_xh<<<32768, 256, 0, stream>>>(x, h, xh);
    for (int i = 0; i < 9; ++i) {
        const int N = (i % 3 == 2) ? 1024 : 512;
        transpose_w<<<dim3(N / 32, 64, 1), 256, 0, stream>>>(Wf[i], WT + wtoff[i], N);
    }
    for (int g = 0; g < 3; ++g)
        concat_bias<<<8, 256, 0, stream>>>(bia[g * 3 + 0], bia[g * 3 + 1], bia[g * 3 + 2], bct + g * 2048);

    const float scscale = 0.044194173824159216f; // 1/sqrt(512)

    auto gate = [&](int g, int epi) {
        const unsigned short* wT = WT + wtoff[g * 3 + 0];
        // fused QKV projection: (32768 x 2048) @ (2048 x 2048)^T, XCD-swizzled
        gemm256<EPI_BF16, 1><<<dim3(8, 128, 1), 512, LDS_BYTES, stream>>>(
            xh, 0, 2048, wT, 0, 2048, bct + g * 2048, QKV, 0, 2048, 2048, 0.0f, nullptr, nullptr);
        transpose_v<<<dim3(32, 16, 64), 256, 0, stream>>>(QKV + 1024, Vt);
        // scores = Q @ K^T * scale (batched over 64)
        gemm256<EPI_SCORES, 0><<<dim3(2, 2, 64), 512, LDS_BYTES, stream>>>(
            QKV, 1048576, 2048, QKV + 512, 1048576, 2048, nullptr,
            Sc, 262144, 512, 512, scscale, nullptr, nullptr);
        softmax512<<<8192, 256, 0, stream>>>(Sc, Pb);
        // PV (batched), fused gate epilogue
        if (epi == EPI_Z)
            gemm256<EPI_Z, 0><<<dim3(4, 2, 64), 512, LDS_BYTES, stream>>>(
                Pb, 262144, 512, Vt, 524288, 512, nullptr, upd, 0, 1024, 512, 0.0f, nullptr, nullptr);
        else if (epi == EPI_R)
            gemm256<EPI_R, 0><<<dim3(4, 2, 64), 512, LDS_BYTES, stream>>>(
                Pb, 262144, 512, Vt, 524288, 512, nullptr, xh, 0, 2048, 512, 0.0f, h, nullptr);
        else
            gemm256<EPI_N, 0><<<dim3(4, 2, 64), 512, LDS_BYTES, stream>>>(
                Pb, 262144, 512, Vt, 524288, 512, nullptr, out, 0, 1024, 512, 0.0f, h, upd);
    };

    gate(1, EPI_Z);  // update = sigmoid(z-attn)            (reads original xh)
    gate(0, EPI_R);  // xh[:,1024:] = bf16(h * sigmoid(r))  (in-place -> xhr)
    gate(2, EPI_N);  // out = (1-u)*h + u*tanh(n-attn)
    layernorm1024<<<8192, 256, 0, stream>>>(out, gamma, beta);
}

// Round 6
// 1295.308 us; speedup vs baseline: 1.5270x; 1.0863x over previous
//
#include <hip/hip_runtime.h>
#include <math.h>

typedef __attribute__((ext_vector_type(8))) short short8;
typedef __attribute__((ext_vector_type(4))) float f32x4;

#define EPI_QKV   0
#define EPI_PEXP  1
#define EPI_R     2
#define EPI_Z     3
#define EPI_N     4

__device__ __forceinline__ unsigned short f2bf(float f) {
    unsigned int u = __float_as_uint(f);
    u += 0x7fffu + ((u >> 16) & 1u);
    return (unsigned short)(u >> 16);
}
__device__ __forceinline__ float bf2f(unsigned short s) {
    return __uint_as_float(((unsigned int)s) << 16);
}

struct alignas(8) us4 { unsigned short a, b, c, d; };

#define GLD_LDS16(gp, lp) \
    __builtin_amdgcn_global_load_lds((const __attribute__((address_space(1))) unsigned int*)(gp), \
                                     (__attribute__((address_space(3))) unsigned int*)(lp), 16, 0, 0)

#define BAR   do { asm volatile("" ::: "memory"); __builtin_amdgcn_s_barrier(); \
                   asm volatile("" ::: "memory"); } while (0)
#define VMC4  asm volatile("s_waitcnt vmcnt(4)" ::: "memory")
#define VMC0  asm volatile("s_waitcnt vmcnt(0)" ::: "memory")

// ============================================================================
// 256x256 tile, BK=64, 512 threads (8 waves: 2M x 4N). Round-5 schedule
// (5 barriers/K-tile, staging spread 2 gload_lds/phase, vmcnt(4)/K-tile).
// Epilogues:
//  EPI_QKV : bx<4 -> QK buffer (bf16, ld 1024); bx>=4 -> direct V^T store
//  EPI_PEXP: P~ = exp(s*scale) bf16 (no max-sub; |s| small) + per-row
//            partial sums -> psum[bx][32768] (shfl + LDS reduce, no atomics)
//  EPI_R/Z/N: divide by (psum[0]+psum[1]) then gate math
// ============================================================================
template<int EPI, int SWZ>
__global__ void __launch_bounds__(512, 2)
gemm256(const unsigned short* __restrict__ A, long long sAb, int lda,
        const unsigned short* __restrict__ Bt, long long sBb, int ldb,
        const float* __restrict__ bias,
        void* __restrict__ C, long long sCb, int ldc,
        int K, float scale,
        const float* __restrict__ hptr,
        const unsigned short* __restrict__ updptr,
        float* __restrict__ psum,
        unsigned short* __restrict__ vt)
{
    extern __shared__ char smem[];   // 131072 B

    const int z = blockIdx.z;
    A  += (size_t)z * (size_t)sAb;
    Bt += (size_t)z * (size_t)sBb;

    int bx, by;
    if (SWZ) {
        const int bid = blockIdx.y * 8 + blockIdx.x;   // grid (8,128)
        const int xcd = bid & 7, i = bid >> 3;
        bx = i & 7;
        by = (xcd << 4) | (i >> 3);
    } else {
        bx = blockIdx.x; by = blockIdx.y;
    }
    const int m0 = by * 256;
    const int n0 = bx * 256;

    const int tid = threadIdx.x;
    const int w  = tid >> 6;      // wave 0..7
    const int l  = tid & 63;
    const int wr = w >> 2;        // 0..1 (M half: 128 rows)
    const int wc = w & 3;         // 0..3 (N quarter: 64 cols)
    const int lr = l & 15;
    const int lg = l >> 4;
    const int rs = (lr & 7) << 4; // read-side XOR swizzle

    const int srw = l >> 3;                        // staging row-within-8
    const int scb = ((l & 7) << 4) ^ (srw << 4);   // inverse-swizzled src col byte

    const long long ldab = (long long)lda * 2;
    const long long ldbb = (long long)ldb * 2;

    f32x4 acc[2][4][4] = {};
    short8 a[4][2], b[4][2];

#define STAGE1(gbase, ldbytes, grow0, ldsoff) { \
    const char* g_ = (const char*)(gbase) + \
        (size_t)((grow0) + w*8 + srw) * (ldbytes) + scb; \
    GLD_LDS16(g_, smem + (ldsoff) + (w << 10)); }

#define AOFF(buf) ((buf)*65536)
#define BOFF(buf) ((buf)*65536 + 32768)

#define LDA8(MH, buf) { \
    const char* Ab_ = smem + AOFF(buf); \
    _Pragma("unroll") \
    for (int mf = 0; mf < 4; ++mf) { \
        const int row_ = wr*128 + (MH)*64 + mf*16 + lr; \
        _Pragma("unroll") \
        for (int kk = 0; kk < 2; ++kk) \
            a[mf][kk] = *(const short8*)(Ab_ + row_*128 + ((kk*64 + lg*16) ^ rs)); } }

#define LDB4(BH, buf) { \
    const char* Bb_ = smem + BOFF(buf); \
    _Pragma("unroll") \
    for (int nf = 0; nf < 2; ++nf) { \
        const int row_ = wc*64 + (BH)*32 + nf*16 + lr; \
        _Pragma("unroll") \
        for (int kk = 0; kk < 2; ++kk) \
            b[(BH)*2+nf][kk] = *(const short8*)(Bb_ + row_*128 + ((kk*64 + lg*16) ^ rs)); } }

#define MMA16(MH, BH) { \
    __builtin_amdgcn_s_setprio(1); \
    _Pragma("unroll") \
    for (int kk = 0; kk < 2; ++kk) \
    _Pragma("unroll") \
    for (int mf = 0; mf < 4; ++mf) \
    _Pragma("unroll") \
    for (int nf = 0; nf < 2; ++nf) \
        acc[MH][mf][(BH)*2+nf] = __builtin_amdgcn_mfma_f32_16x16x32_bf16( \
            a[mf][kk], b[(BH)*2+nf][kk], acc[MH][mf][(BH)*2+nf], 0, 0, 0); \
    __builtin_amdgcn_s_setprio(0); }

    // prologue: tile0 (all 4 slots) -> buf0; tile1 A-slots -> buf1.
    {
        STAGE1(A,        ldab, m0 + 0,   AOFF(0) + 0);
        STAGE1(A,        ldab, m0 + 128, AOFF(0) + 16384);
        STAGE1(A,        ldab, m0 + 64,  AOFF(0) + 8192);
        STAGE1(A,        ldab, m0 + 192, AOFF(0) + 24576);
        STAGE1(Bt,       ldbb, n0 + 0,   BOFF(0) + 0);
        STAGE1(Bt,       ldbb, n0 + 128, BOFF(0) + 16384);
        STAGE1(Bt,       ldbb, n0 + 64,  BOFF(0) + 8192);
        STAGE1(Bt,       ldbb, n0 + 192, BOFF(0) + 24576);
        STAGE1(A + 64,   ldab, m0 + 0,   AOFF(1) + 0);
        STAGE1(A + 64,   ldab, m0 + 128, AOFF(1) + 16384);
        STAGE1(A + 64,   ldab, m0 + 64,  AOFF(1) + 8192);
        STAGE1(A + 64,   ldab, m0 + 192, AOFF(1) + 24576);
        VMC4;
        BAR;
    }

    const int NT = K >> 6;
    for (int t = 0; t < NT; ++t) {
        const int p = t & 1, q = p ^ 1;
        const unsigned short* An = A  + (size_t)(t + 2) * 64;
        const unsigned short* Bn = Bt + (size_t)(t + 1) * 64;
        const bool sB = (t + 1 < NT), sA = (t + 2 < NT);

        // ph0
        LDA8(0, p); LDB4(0, p);
        if (sB) { STAGE1(Bn, ldbb, n0 + 0,   BOFF(q) + 0);
                  STAGE1(Bn, ldbb, n0 + 128, BOFF(q) + 16384); }
        BAR;
        MMA16(0, 0);
        // ph1
        LDB4(1, p);
        if (sB) { STAGE1(Bn, ldbb, n0 + 64,  BOFF(q) + 8192);
                  STAGE1(Bn, ldbb, n0 + 192, BOFF(q) + 24576); }
        BAR;
        MMA16(0, 1);
        // ph2
        LDA8(1, p);
        if (sA) { STAGE1(An, ldab, m0 + 0,   AOFF(p) + 0);
                  STAGE1(An, ldab, m0 + 128, AOFF(p) + 16384); }
        BAR;
        MMA16(1, 1);
        BAR;                       // guards ph3-stage vs ph2-reads
        // ph3
        if (sA) { STAGE1(An, ldab, m0 + 64,  AOFF(p) + 8192);
                  STAGE1(An, ldab, m0 + 192, AOFF(p) + 24576);
                  VMC4; }
        else if (sB) { VMC0; }
        BAR;
        MMA16(1, 0);
    }

    // ======================= epilogues =======================
    const int Mb = gridDim.y << 8;          // rows per batch slab
    const size_t zc = (size_t)z * (size_t)sCb;

    if (EPI == EPI_PEXP) {
        float psl[2][4][4];
        #pragma unroll
        for (int mh = 0; mh < 2; ++mh)
            #pragma unroll
            for (int mf = 0; mf < 4; ++mf)
                #pragma unroll
                for (int r = 0; r < 4; ++r) psl[mh][mf][r] = 0.0f;

        #pragma unroll
        for (int mh = 0; mh < 2; ++mh)
        #pragma unroll
        for (int mf = 0; mf < 4; ++mf)
        #pragma unroll
        for (int nf = 0; nf < 4; ++nf) {
            const int col = n0 + wc * 64 + nf * 16 + lr;
            #pragma unroll
            for (int r = 0; r < 4; ++r) {
                const int row = m0 + wr * 128 + mh * 64 + mf * 16 + lg * 4 + r;
                const float e = __expf(acc[mh][mf][nf][r] * scale);
                ((unsigned short*)C)[zc + (size_t)row * ldc + col] = f2bf(e);
                psl[mh][mf][r] += e;
            }
        }
        // reduce over the 16 col-lanes (lr); lanes stay inside their lg group
        #pragma unroll
        for (int d = 1; d < 16; d <<= 1)
            #pragma unroll
            for (int mh = 0; mh < 2; ++mh)
                #pragma unroll
                for (int mf = 0; mf < 4; ++mf)
                    #pragma unroll
                    for (int r = 0; r < 4; ++r)
                        psl[mh][mf][r] += __shfl_xor(psl[mh][mf][r], d);
        __syncthreads();                       // main-loop LDS fully consumed
        float* red = (float*)smem;             // [4 waves][256 rows]
        if (lr == 0) {
            #pragma unroll
            for (int mh = 0; mh < 2; ++mh)
                #pragma unroll
                for (int mf = 0; mf < 4; ++mf)
                    #pragma unroll
                    for (int r = 0; r < 4; ++r)
                        red[wc * 256 + wr * 128 + mh * 64 + mf * 16 + lg * 4 + r]
                            = psl[mh][mf][r];
        }
        __syncthreads();
        if (tid < 256) {
            const float sres = red[tid] + red[256 + tid] + red[512 + tid] + red[768 + tid];
            psum[(size_t)bx * 32768 + (size_t)z * 512 + m0 + tid] = sres;
        }
        return;
    }

    float invs[2][4][4];
    if (EPI == EPI_R || EPI == EPI_Z || EPI == EPI_N) {
        #pragma unroll
        for (int mh = 0; mh < 2; ++mh)
            #pragma unroll
            for (int mf = 0; mf < 4; ++mf)
                #pragma unroll
                for (int r = 0; r < 4; ++r) {
                    const int row = m0 + wr * 128 + mh * 64 + mf * 16 + lg * 4 + r;
                    const size_t gr = (size_t)z * 512 + row;
                    invs[mh][mf][r] = 1.0f / (psum[gr] + psum[32768 + gr]);
                }
    }

    #pragma unroll
    for (int mh = 0; mh < 2; ++mh) {
        #pragma unroll
        for (int mf = 0; mf < 4; ++mf) {
            #pragma unroll
            for (int nf = 0; nf < 4; ++nf) {
                const int col = n0 + wc * 64 + nf * 16 + lr;
                const float bval = (EPI == EPI_QKV) ? bias[col] : 0.0f;
                if (EPI == EPI_QKV && bx >= 4) {
                    // direct V^T store: 4 consecutive channel-rows at fixed v-dim
                    const int row0 = m0 + wr * 128 + mh * 64 + mf * 16 + lg * 4;
                    us4 o = { f2bf(acc[mh][mf][nf][0] + bval),
                              f2bf(acc[mh][mf][nf][1] + bval),
                              f2bf(acc[mh][mf][nf][2] + bval),
                              f2bf(acc[mh][mf][nf][3] + bval) };
                    *(us4*)(vt + (size_t)(row0 >> 9) * 524288 +
                            (size_t)(col - 1024) * 512 + (row0 & 511)) = o;
                } else {
                    #pragma unroll
                    for (int r = 0; r < 4; ++r) {
                        const int row = m0 + wr * 128 + mh * 64 + mf * 16 + lg * 4 + r;
                        float v = acc[mh][mf][nf][r] + bval;
                        if (EPI == EPI_QKV) {
                            ((unsigned short*)C)[(size_t)row * ldc + col] = f2bf(v);
                        } else if (EPI == EPI_R) {
                            v *= invs[mh][mf][r];
                            const size_t flat = (size_t)z * Mb + row;
                            const float hh = hptr[flat * 1024 + col];
                            const float sg = 1.0f / (1.0f + __expf(-v));
                            ((unsigned short*)C)[flat * 2048 + 1024 + col] = f2bf(hh * sg);
                        } else if (EPI == EPI_Z) {
                            v *= invs[mh][mf][r];
                            const size_t flat = (size_t)z * Mb + row;
                            const float sg = 1.0f / (1.0f + __expf(-v));
                            ((unsigned short*)C)[flat * 1024 + col] = f2bf(sg);
                        } else { // EPI_N
                            v *= invs[mh][mf][r];
                            const size_t flat = (size_t)z * Mb + row;
                            const float u  = bf2f(updptr[flat * 1024 + col]);
                            const float hh = hptr[flat * 1024 + col];
                            ((float*)C)[flat * 1024 + col] = (1.0f - u) * hh + u * tanhf(v);
                        }
                    }
                }
            }
        }
    }
#undef STAGE1
#undef AOFF
#undef BOFF
#undef LDA8
#undef LDB4
#undef MMA16
}

// ============================================================================
// memory-bound helper kernels
// ============================================================================

__global__ void __launch_bounds__(256)
prep_xh(const float* __restrict__ x, const float* __restrict__ h, unsigned short* __restrict__ xh)
{
    const size_t t = (size_t)blockIdx.x * 256 + threadIdx.x;
    const size_t f = t * 4;
    const size_t row = f >> 10, col = f & 1023;
    const float4 vx = *(const float4*)(x + f);
    const float4 vh = *(const float4*)(h + f);
    us4 ox = { f2bf(vx.x), f2bf(vx.y), f2bf(vx.z), f2bf(vx.w) };
    us4 oh = { f2bf(vh.x), f2bf(vh.y), f2bf(vh.z), f2bf(vh.w) };
    *(us4*)(xh + row * 2048 + col)        = ox;
    *(us4*)(xh + row * 2048 + 1024 + col) = oh;
}

__global__ void __launch_bounds__(256)
transpose_w(const float* __restrict__ W, unsigned short* __restrict__ WT, int N)
{
    __shared__ float t[32][33];
    const int k0 = blockIdx.y * 32, n0 = blockIdx.x * 32;
    const int tx = threadIdx.x & 31, ty = threadIdx.x >> 5;
    #pragma unroll
    for (int i = 0; i < 4; ++i)
        t[ty + i * 8][tx] = W[(size_t)(k0 + ty + i * 8) * N + n0 + tx];
    __syncthreads();
    #pragma unroll
    for (int i = 0; i < 4; ++i)
        WT[(size_t)(n0 + ty + i * 8) * 2048 + k0 + tx] = f2bf(t[tx][ty + i * 8]);
}

__global__ void __launch_bounds__(256)
layernorm1024(float* __restrict__ Y, const float* __restrict__ gamma, const float* __restrict__ beta)
{
    const int row = blockIdx.x * 4 + (threadIdx.x >> 6);
    const int l = threadIdx.x & 63;
    float* p = Y + (size_t)row * 1024;
    float4 v[4];
    float s = 0.0f, s2 = 0.0f;
    #pragma unroll
    for (int i = 0; i < 4; ++i) {
        v[i] = ((const float4*)p)[i * 64 + l];
        s  += v[i].x + v[i].y + v[i].z + v[i].w;
        s2 += v[i].x * v[i].x + v[i].y * v[i].y + v[i].z * v[i].z + v[i].w * v[i].w;
    }
    #pragma unroll
    for (int d = 32; d; d >>= 1) { s += __shfl_xor(s, d); s2 += __shfl_xor(s2, d); }
    const float mu = s * (1.0f / 1024.0f);
    const float var = s2 * (1.0f / 1024.0f) - mu * mu;
    const float inv = rsqrtf(var + 1e-5f);
    #pragma unroll
    for (int i = 0; i < 4; ++i) {
        const float4 gv = ((const float4*)gamma)[i * 64 + l];
        const float4 bv = ((const float4*)beta)[i * 64 + l];
        float4 o;
        o.x = (v[i].x - mu) * inv * gv.x + bv.x;
        o.y = (v[i].y - mu) * inv * gv.y + bv.y;
        o.z = (v[i].z - mu) * inv * gv.z + bv.z;
        o.w = (v[i].w - mu) * inv * gv.w + bv.w;
        ((float4*)p)[i * 64 + l] = o;
    }
}

__global__ void __launch_bounds__(256)
concat_bias(const float* __restrict__ a, const float* __restrict__ b,
            const float* __restrict__ c, float* __restrict__ o)
{
    const int i = blockIdx.x * 256 + threadIdx.x;
    o[i] = (i < 512) ? a[i] : (i < 1024) ? b[i - 512] : c[i - 1024];
}

extern "C" void kernel_launch(void* const* d_in, const int* in_sizes, int n_in,
                              void* d_out, int out_size, void* d_ws, size_t ws_size,
                              hipStream_t stream)
{
    (void)in_sizes; (void)n_in; (void)out_size; (void)ws_size;

    const float* x = (const float*)d_in[0];
    const float* h = (const float*)d_in[1];
    const float* Wf[9]; const float* bia[9];
    for (int g = 0; g < 3; ++g)
        for (int j = 0; j < 3; ++j) {
            Wf[g * 3 + j]  = (const float*)d_in[2 + g * 6 + j * 2];
            bia[g * 3 + j] = (const float*)d_in[2 + g * 6 + j * 2 + 1];
        }
    const float* gamma = (const float*)d_in[20];
    const float* beta  = (const float*)d_in[21];
    float* out = (float*)d_out;

    const int LDS_BYTES = 131072;
    hipFuncSetAttribute((const void*)gemm256<EPI_QKV, 1>,  hipFuncAttributeMaxDynamicSharedMemorySize, LDS_BYTES);
    hipFuncSetAttribute((const void*)gemm256<EPI_PEXP, 0>, hipFuncAttributeMaxDynamicSharedMemorySize, LDS_BYTES);
    hipFuncSetAttribute((const void*)gemm256<EPI_R, 0>,    hipFuncAttributeMaxDynamicSharedMemorySize, LDS_BYTES);
    hipFuncSetAttribute((const void*)gemm256<EPI_Z, 0>,    hipFuncAttributeMaxDynamicSharedMemorySize, LDS_BYTES);
    hipFuncSetAttribute((const void*)gemm256<EPI_N, 0>,    hipFuncAttributeMaxDynamicSharedMemorySize, LDS_BYTES);

    char* ws = (char*)d_ws;
    size_t off = 0;
    auto alloc = [&](size_t bytes) -> void* {
        void* p = ws + off; off += (bytes + 255) & ~(size_t)255; return p;
    };
    unsigned short* xh  = (unsigned short*)alloc((size_t)32768 * 2048 * 2); // 134 MB
    unsigned short* WT  = (unsigned short*)alloc((size_t)12582912 * 2);     // 24 MB
    unsigned short* QK  = (unsigned short*)alloc((size_t)32768 * 1024 * 2); // 67 MB
    unsigned short* Vt  = (unsigned short*)alloc((size_t)32768 * 1024 * 2); // 67 MB
    unsigned short* Pb  = (unsigned short*)alloc((size_t)64 * 512 * 512 * 2);// 33.5 MB
    unsigned short* upd = (unsigned short*)alloc((size_t)32768 * 1024 * 2); // 67 MB
    float*          psb = (float*)alloc((size_t)2 * 32768 * 4);             // 256 KB
    float*          bct = (float*)alloc((size_t)3 * 2048 * 4);

    size_t wtoff[9];
    {
        size_t o = 0;
        for (int g = 0; g < 3; ++g) {
            wtoff[g * 3 + 0] = o; o += (size_t)512 * 2048;
            wtoff[g * 3 + 1] = o; o += (size_t)512 * 2048;
            wtoff[g * 3 + 2] = o; o += (size_t)1024 * 2048;
        }
    }

    prep_xh<<<32768, 256, 0, stream>>>(x, h, xh);
    for (int i = 0; i < 9; ++i) {
        const int N = (i % 3 == 2) ? 1024 : 512;
        transpose_w<<<dim3(N / 32, 64, 1), 256, 0, stream>>>(Wf[i], WT + wtoff[i], N);
    }
    for (int g = 0; g < 3; ++g)
        concat_bias<<<8, 256, 0, stream>>>(bia[g * 3 + 0], bia[g * 3 + 1], bia[g * 3 + 2], bct + g * 2048);

    const float scscale = 0.044194173824159216f; // 1/sqrt(512)

    auto gate = [&](int g, int epi) {
        const unsigned short* wT = WT + wtoff[g * 3 + 0];
        // fused QKV projection (N=2048): Q,K -> QK buffer; V -> Vt (transposed store)
        gemm256<EPI_QKV, 1><<<dim3(8, 128, 1), 512, LDS_BYTES, stream>>>(
            xh, 0, 2048, wT, 0, 2048, bct + g * 2048,
            QK, 0, 1024, 2048, 0.0f, nullptr, nullptr, nullptr, Vt);
        // P~ = exp(Q@K^T * scale) + per-row partial sums (batched over 64)
        gemm256<EPI_PEXP, 0><<<dim3(2, 2, 64), 512, LDS_BYTES, stream>>>(
            QK, 524288, 1024, QK + 512, 524288, 1024, nullptr,
            Pb, 262144, 512, 512, scscale, nullptr, nullptr, psb, nullptr);
        // PV (batched), rowsum-normalized, fused gate epilogue
        if (epi == EPI_Z)
            gemm256<EPI_Z, 0><<<dim3(4, 2, 64), 512, LDS_BYTES, stream>>>(
                Pb, 262144, 512, Vt, 524288, 512, nullptr,
                upd, 0, 1024, 512, 0.0f, nullptr, nullptr, psb, nullptr);
        else if (epi == EPI_R)
            gemm256<EPI_R, 0><<<dim3(4, 2, 64), 512, LDS_BYTES, stream>>>(
                Pb, 262144, 512, Vt, 524288, 512, nullptr,
                xh, 0, 2048, 512, 0.0f, h, nullptr, psb, nullptr);
        else
            gemm256<EPI_N, 0><<<dim3(4, 2, 64), 512, LDS_BYTES, stream>>>(
                Pb, 262144, 512, Vt, 524288, 512, nullptr,
                out, 0, 1024, 512, 0.0f, h, upd, psb, nullptr);
    };

    gate(1, EPI_Z);  // update = sigmoid(z-attn)            (reads original xh)
    gate(0, EPI_R);  // xh[:,1024:] = bf16(h * sigmoid(r))  (in-place -> xhr)
    gate(2, EPI_N);  // out = (1-u)*h + u*tanh(n-attn)
    layernorm1024<<<8192, 256, 0, stream>>>(out, gamma, beta);
}